// Round 4
// baseline (127.615 us; speedup 1.0000x reference)
//
#include <hip/hip_runtime.h>
#include <hip/hip_bf16.h>

typedef __attribute__((ext_vector_type(8))) short short8;
typedef __attribute__((ext_vector_type(4))) float f32x4;

#define N1 768
#define N2 768
#define LL 128
#define NS 30

// float -> bf16 bits, round-to-nearest-even (proven rounds 1-2)
__device__ __forceinline__ unsigned short f2b(float f) {
  unsigned int u = __float_as_uint(f);
  unsigned int r = (u + 0x7fffu + ((u >> 16) & 1u)) >> 16;
  return (unsigned short)r;
}

__device__ __forceinline__ float b2f(unsigned short b) {
  return __uint_as_float(((unsigned int)b) << 16);
}

// ---------------------------------------------------------------------------
// prep: blocks 1..32: w = sigmoid(W) (f32 + bf16).
//       block 0: Sdiag[s] = ||A[s]||^2; split tables
//         Thl=[hi|lo], Thh=[hi|hi], Tl0=[lo|0]
//       rows padded to 40 ushorts (80 B = 5*16, keeps 16B alignment).
// ---------------------------------------------------------------------------
__global__ void prep_kernel(const float* __restrict__ A, const float* __restrict__ w_vec,
                            float* __restrict__ wf, unsigned short* __restrict__ wb,
                            float* __restrict__ Sdiag, unsigned short* __restrict__ Tg) {
  int b = blockIdx.x, t = threadIdx.x;
  if (b == 0) {
    unsigned short* Thl = Tg;
    unsigned short* Thh = Tg + 1200;
    unsigned short* Tl0 = Tg + 2400;
    for (int idx = t; idx < NS * 16; idx += 256) {
      int s = idx >> 4, c = idx & 15;
      float v = A[idx];
      unsigned short hi = f2b(v);
      unsigned short lo = f2b(v - b2f(hi));
      Thl[s * 40 + c] = hi;  Thl[s * 40 + 16 + c] = lo;
      Thh[s * 40 + c] = hi;  Thh[s * 40 + 16 + c] = hi;
      Tl0[s * 40 + c] = lo;  Tl0[s * 40 + 16 + c] = 0;
      if (c < 8) {
        Thl[s * 40 + 32 + c] = 0;
        Thh[s * 40 + 32 + c] = 0;
        Tl0[s * 40 + 32 + c] = 0;
      }
    }
    if (t < NS) {
      float acc = 0.f;
#pragma unroll
      for (int c = 0; c < 16; ++c) { float v = A[t * 16 + c]; acc += v * v; }
      Sdiag[t] = acc;
    }
  } else {
    int base = (b - 1) * 512;
#pragma unroll
    for (int k = 0; k < 2; ++k) {
      int idx = base + k * 256 + t;
      int l = idx >> 7, mm = idx & (LL - 1);
      float sig;
      if (l == mm) {
        sig = 0.5f;
      } else {
        int hi = l > mm ? l : mm, lo = l > mm ? mm : l;
        sig = 1.f / (1.f + expf(-w_vec[hi * (hi - 1) / 2 + lo]));
      }
      wf[idx] = sig;
      wb[idx] = f2b(sig);
    }
  }
}

// ---------------------------------------------------------------------------
// norm: one block per row (0..767 -> inv1 with a^2, 768..1535 -> inv2)
// ---------------------------------------------------------------------------
__global__ void norm_kernel(const int* __restrict__ X1, const int* __restrict__ X2,
                            const float* __restrict__ Sdiag, const float* __restrict__ wf,
                            float* __restrict__ inv1, float* __restrict__ inv2,
                            const float* __restrict__ a_ptr) {
  __shared__ __align__(16) float d[LL];
  __shared__ float wsum[2];
  int row = blockIdx.x, t = threadIdx.x;
  const int* X = (row < N1) ? (X1 + row * LL) : (X2 + (row - N1) * LL);
  float dv = Sdiag[X[t]];
  d[t] = dv;
  __syncthreads();
  const float4* w4 = reinterpret_cast<const float4*>(wf + t * LL);
  const float4* d4 = reinterpret_cast<const float4*>(d);
  float s = 0.f;
#pragma unroll
  for (int q = 0; q < LL / 4; ++q) {
    float4 wv = w4[q];
    float4 dd = d4[q];
    s += wv.x * dd.x + wv.y * dd.y + wv.z * dd.z + wv.w * dd.w;
  }
  s *= dv;
#pragma unroll
  for (int off = 1; off < 64; off <<= 1) s += __shfl_xor(s, off);
  if ((t & 63) == 0) wsum[t >> 6] = s;
  __syncthreads();
  if (t == 0) {
    float k = wsum[0] + wsum[1];
    if (row < N1) inv1[row] = a_ptr[0] * a_ptr[0] / sqrtf(k);
    else inv2[row - N1] = 1.f / sqrtf(k);
  }
}

// ---------------------------------------------------------------------------
// main: one block = 16x16 output tile (256 pairs), 512 threads (8 waves).
//  W held in registers (wreg[8][4], from global, L1-resident).
//  phase2 (round-2 numerics): per l, 2 MFMA with shared A-frag:
//    V_l = [hi1|lo1]@[hi2|hi2]^T + [hi1|lo1]@[lo2|0]^T  (drops only lo*lo)
//    f2b pack -> swizzled sV uint2 writes.
//  phase3: E^T = W @ V^T; wave owns p in {wave*32+m, +16}: V B-frags are
//    lt-invariant (8 b128 total). Epilogue folded into lt loop:
//    kp += sum_r accT[r] * V[p][lt*16+kg*4+r] (one b64 read),
//    shfl-xor(16,32) reduce over kg, store.
// ---------------------------------------------------------------------------
__global__ __launch_bounds__(512, 2) void main_kernel(
    const int* __restrict__ X1, const int* __restrict__ X2,
    const unsigned short* __restrict__ wbg, const unsigned short* __restrict__ Tg,
    const float* __restrict__ inv1, const float* __restrict__ inv2,
    float* __restrict__ out) {
  __shared__ __align__(16) unsigned short sV[256 * LL];  // 64 KB, swizzled
  __shared__ __align__(16) unsigned short sT[3600];      // Thl|Thh|Tl0 (7200 B)
  __shared__ __align__(16) unsigned char x1B[16 * 136];  // bytes [row][l]
  __shared__ __align__(16) unsigned char x2B[16 * 136];

  const int t = threadIdx.x;
  const int lane = t & 63, wave = t >> 6;
  const int m = lane & 15, kg = lane >> 4;
  const int i0 = blockIdx.y * 16, j0 = blockIdx.x * 16;
  char* sVb = reinterpret_cast<char*>(sV);
  char* sTb = reinterpret_cast<char*>(sT);

  // ---- W fragments into registers (A-side of E^T = W @ V^T) ----
  short8 wreg[8][4];
#pragma unroll
  for (int lt = 0; lt < 8; ++lt)
#pragma unroll
    for (int kk = 0; kk < 4; ++kk)
      wreg[lt][kk] = *reinterpret_cast<const short8*>(
          reinterpret_cast<const char*>(wbg) + (lt * 16 + m) * 256 + kk * 64 + kg * 16);

  // ---- normalization scalars early ----
  float iv2 = inv2[j0 + m];
  float iv1a = inv1[i0 + wave * 2];
  float iv1b = inv1[i0 + wave * 2 + 1];

  // ---- stage split tables (7200 B = 450 uint4) ----
  if (t < 450) reinterpret_cast<uint4*>(sT)[t] = reinterpret_cast<const uint4*>(Tg)[t];

  // ---- stage X rows as bytes [row][l], pad 136 ----
  if (t < 256) {
    int row = t >> 4, seg = t & 15;
    const int4* p1 = reinterpret_cast<const int4*>(X1 + (i0 + row) * LL + seg * 8);
    int4 a0 = p1[0], a1 = p1[1];
    unsigned long long v = 0;
    v |= (unsigned long long)(a0.x & 0xff);
    v |= (unsigned long long)(a0.y & 0xff) << 8;
    v |= (unsigned long long)(a0.z & 0xff) << 16;
    v |= (unsigned long long)(a0.w & 0xff) << 24;
    v |= (unsigned long long)(a1.x & 0xff) << 32;
    v |= (unsigned long long)(a1.y & 0xff) << 40;
    v |= (unsigned long long)(a1.z & 0xff) << 48;
    v |= (unsigned long long)(a1.w & 0xff) << 56;
    *reinterpret_cast<unsigned long long*>(x1B + row * 136 + seg * 8) = v;
    const int4* p2 = reinterpret_cast<const int4*>(X2 + (j0 + row) * LL + seg * 8);
    int4 b0 = p2[0], b1 = p2[1];
    unsigned long long u = 0;
    u |= (unsigned long long)(b0.x & 0xff);
    u |= (unsigned long long)(b0.y & 0xff) << 8;
    u |= (unsigned long long)(b0.z & 0xff) << 16;
    u |= (unsigned long long)(b0.w & 0xff) << 24;
    u |= (unsigned long long)(b1.x & 0xff) << 32;
    u |= (unsigned long long)(b1.y & 0xff) << 40;
    u |= (unsigned long long)(b1.z & 0xff) << 48;
    u |= (unsigned long long)(b1.w & 0xff) << 56;
    *reinterpret_cast<unsigned long long*>(x2B + row * 136 + seg * 8) = u;
  }
  __syncthreads();

  // ---- phase 2: V-build. wave owns l in [16w, 16w+16) ----
  {
    const int lbase = wave * 16;
#pragma unroll
    for (int lb = 0; lb < 4; ++lb) {
      int l0 = lbase + lb * 4;
      unsigned int w1 = *reinterpret_cast<const unsigned int*>(x1B + m * 136 + l0);
      unsigned int w2 = *reinterpret_cast<const unsigned int*>(x2B + m * 136 + l0);
      f32x4 vq[4];
#pragma unroll
      for (int q = 0; q < 4; ++q) {
        int i1 = (w1 >> (8 * q)) & 0xff;
        int i2 = (w2 >> (8 * q)) & 0xff;
        short8 af = *reinterpret_cast<const short8*>(sTb + i1 * 80 + kg * 16);
        short8 bf1 = *reinterpret_cast<const short8*>(sTb + 2400 + i2 * 80 + kg * 16);
        short8 bf2 = *reinterpret_cast<const short8*>(sTb + 4800 + i2 * 80 + kg * 16);
        f32x4 z = {0.f, 0.f, 0.f, 0.f};
        z = __builtin_amdgcn_mfma_f32_16x16x32_bf16(af, bf1, z, 0, 0, 0);
        z = __builtin_amdgcn_mfma_f32_16x16x32_bf16(af, bf2, z, 0, 0, 0);
        vq[q] = z;
      }
#pragma unroll
      for (int r = 0; r < 4; ++r) {
        uint2 pk;
        pk.x = (unsigned int)f2b(vq[0][r]) | ((unsigned int)f2b(vq[1][r]) << 16);
        pk.y = (unsigned int)f2b(vq[2][r]) | ((unsigned int)f2b(vq[3][r]) << 16);
        int p = (kg * 4 + r) * 16 + m;
        *reinterpret_cast<uint2*>(sVb + p * 256 + ((2 * l0) ^ ((p & 7) << 4))) = pk;
      }
    }
  }
  __syncthreads();

  // ---- phase 3: E^T = W @ V^T with folded epilogue ----
  const int pA = (wave * 2) * 16 + m;
  const int pB = (wave * 2 + 1) * 16 + m;
  short8 bvA[4], bvB[4];
#pragma unroll
  for (int kk = 0; kk < 4; ++kk) {
    bvA[kk] = *reinterpret_cast<const short8*>(
        sVb + pA * 256 + ((kk * 64 + kg * 16) ^ ((pA & 7) << 4)));
    bvB[kk] = *reinterpret_cast<const short8*>(
        sVb + pB * 256 + ((kk * 64 + kg * 16) ^ ((pB & 7) << 4)));
  }
  float kp0 = 0.f, kp1 = 0.f;
#pragma unroll
  for (int lt = 0; lt < 8; ++lt) {
    f32x4 a0 = {0.f, 0.f, 0.f, 0.f}, a1 = {0.f, 0.f, 0.f, 0.f};
#pragma unroll
    for (int kk = 0; kk < 4; ++kk) {
      a0 = __builtin_amdgcn_mfma_f32_16x16x32_bf16(wreg[lt][kk], bvA[kk], a0, 0, 0, 0);
      a1 = __builtin_amdgcn_mfma_f32_16x16x32_bf16(wreg[lt][kk], bvB[kk], a1, 0, 0, 0);
    }
    {
      uint2 vv = *reinterpret_cast<const uint2*>(
          sVb + pA * 256 + ((32 * lt + 8 * kg) ^ ((pA & 7) << 4)));
      float s0 = __uint_as_float(vv.x << 16);
      float s1 = __uint_as_float(vv.x & 0xffff0000u);
      float s2 = __uint_as_float(vv.y << 16);
      float s3 = __uint_as_float(vv.y & 0xffff0000u);
      kp0 += a0[0] * s0 + a0[1] * s1 + a0[2] * s2 + a0[3] * s3;
    }
    {
      uint2 vv = *reinterpret_cast<const uint2*>(
          sVb + pB * 256 + ((32 * lt + 8 * kg) ^ ((pB & 7) << 4)));
      float s0 = __uint_as_float(vv.x << 16);
      float s1 = __uint_as_float(vv.x & 0xffff0000u);
      float s2 = __uint_as_float(vv.y << 16);
      float s3 = __uint_as_float(vv.y & 0xffff0000u);
      kp1 += a1[0] * s0 + a1[1] * s1 + a1[2] * s2 + a1[3] * s3;
    }
  }
  kp0 += __shfl_xor(kp0, 16);
  kp0 += __shfl_xor(kp0, 32);
  kp1 += __shfl_xor(kp1, 16);
  kp1 += __shfl_xor(kp1, 32);
  if (kg == 0) {
    int gi = i0 + wave * 2, gj = j0 + m;
    out[gi * N2 + gj] = kp0 * iv1a * iv2;
    out[(gi + 1) * N2 + gj] = kp1 * iv1b * iv2;
  }
}

// ---------------------------------------------------------------------------
extern "C" void kernel_launch(void* const* d_in, const int* in_sizes, int n_in,
                              void* d_out, int out_size, void* d_ws, size_t ws_size,
                              hipStream_t stream) {
  const int* X1 = (const int*)d_in[0];
  const int* X2 = (const int*)d_in[1];
  const float* a = (const float*)d_in[2];
  const float* A = (const float*)d_in[3];
  const float* w_vec = (const float*)d_in[4];
  float* out = (float*)d_out;

  char* ws = (char*)d_ws;
  float* wf = (float*)(ws + 0);                        // 64 KB
  unsigned short* wb = (unsigned short*)(ws + 65536);  // 32 KB
  float* Sdiag = (float*)(ws + 98304);                 // 128 B
  unsigned short* Tg = (unsigned short*)(ws + 98432);  // 7200 B
  float* inv1 = (float*)(ws + 105728);                 // 3 KB
  float* inv2 = inv1 + N1;                             // 3 KB

  prep_kernel<<<33, 256, 0, stream>>>(A, w_vec, wf, wb, Sdiag, Tg);
  norm_kernel<<<N1 + N2, 128, 0, stream>>>(X1, X2, Sdiag, wf, inv1, inv2, a);
  main_kernel<<<dim3(N2 / 16, N1 / 16), 512, 0, stream>>>(X1, X2, wb, Tg, inv1, inv2, out);
}

// Round 5
// 72.555 us; speedup vs baseline: 1.7589x; 1.7589x over previous
//
#include <hip/hip_runtime.h>
#include <hip/hip_bf16.h>

typedef __attribute__((ext_vector_type(8))) short short8;
typedef __attribute__((ext_vector_type(4))) float f32x4;

#define N1 768
#define N2 768
#define LL 128
#define NS 30

// float -> bf16 bits, round-to-nearest-even (proven rounds 1-4)
__device__ __forceinline__ unsigned short f2b(float f) {
  unsigned int u = __float_as_uint(f);
  unsigned int r = (u + 0x7fffu + ((u >> 16) & 1u)) >> 16;
  return (unsigned short)r;
}

__device__ __forceinline__ float b2f(unsigned short b) {
  return __uint_as_float(((unsigned int)b) << 16);
}

// ---------------------------------------------------------------------------
// prep: blocks 1..32: w = sigmoid(W) (f32 + bf16).
//       block 0: Sdiag[s] = ||A[s]||^2; split tables
//         Thl=[hi|lo], Thh=[hi|hi], Tl0=[lo|0], 40 ushorts/row (80 B).
//       NEW: each row's four 16B chunks are permuted by chunk ^= (row>>3);
//       combined with the 80B-stride bank partition this makes random-row
//       16B reads exactly conflict-free (distinct rows -> disjoint banks).
// ---------------------------------------------------------------------------
__global__ void prep_kernel(const float* __restrict__ A, const float* __restrict__ w_vec,
                            float* __restrict__ wf, unsigned short* __restrict__ wb,
                            float* __restrict__ Sdiag, unsigned short* __restrict__ Tg) {
  int b = blockIdx.x, t = threadIdx.x;
  if (b == 0) {
    unsigned short* Thl = Tg;
    unsigned short* Thh = Tg + 1200;
    unsigned short* Tl0 = Tg + 2400;
    for (int idx = t; idx < NS * 16; idx += 256) {
      int s = idx >> 4, c = idx & 15, q = s >> 3;
      float v = A[idx];
      unsigned short hi = f2b(v);
      unsigned short lo = f2b(v - b2f(hi));
      int c0 = ((c >> 3) ^ q) * 8 + (c & 7);        // phys slot of logical chunk c>>3
      int c2 = (((c >> 3) + 2) ^ q) * 8 + (c & 7);  // phys slot of logical chunk 2+(c>>3)
      Thl[s * 40 + c0] = hi;  Thl[s * 40 + c2] = lo;
      Thh[s * 40 + c0] = hi;  Thh[s * 40 + c2] = hi;
      Tl0[s * 40 + c0] = lo;  Tl0[s * 40 + c2] = 0;
      if (c < 8) {  // pad chunk 4
        Thl[s * 40 + 32 + c] = 0;
        Thh[s * 40 + 32 + c] = 0;
        Tl0[s * 40 + 32 + c] = 0;
      }
    }
    if (t < NS) {
      float acc = 0.f;
#pragma unroll
      for (int c = 0; c < 16; ++c) { float v = A[t * 16 + c]; acc += v * v; }
      Sdiag[t] = acc;
    }
  } else {
    int base = (b - 1) * 512;
#pragma unroll
    for (int k = 0; k < 2; ++k) {
      int idx = base + k * 256 + t;
      int l = idx >> 7, mm = idx & (LL - 1);
      float sig;
      if (l == mm) {
        sig = 0.5f;
      } else {
        int hi = l > mm ? l : mm, lo = l > mm ? mm : l;
        sig = 1.f / (1.f + expf(-w_vec[hi * (hi - 1) / 2 + lo]));
      }
      wf[idx] = sig;
      wb[idx] = f2b(sig);
    }
  }
}

// ---------------------------------------------------------------------------
// norm: one block per row (0..767 -> inv1 with a^2, 768..1535 -> inv2)
// ---------------------------------------------------------------------------
__global__ void norm_kernel(const int* __restrict__ X1, const int* __restrict__ X2,
                            const float* __restrict__ Sdiag, const float* __restrict__ wf,
                            float* __restrict__ inv1, float* __restrict__ inv2,
                            const float* __restrict__ a_ptr) {
  __shared__ __align__(16) float d[LL];
  __shared__ float wsum[2];
  int row = blockIdx.x, t = threadIdx.x;
  const int* X = (row < N1) ? (X1 + row * LL) : (X2 + (row - N1) * LL);
  float dv = Sdiag[X[t]];
  d[t] = dv;
  __syncthreads();
  const float4* w4 = reinterpret_cast<const float4*>(wf + t * LL);
  const float4* d4 = reinterpret_cast<const float4*>(d);
  float s = 0.f;
#pragma unroll
  for (int q = 0; q < LL / 4; ++q) {
    float4 wv = w4[q];
    float4 dd = d4[q];
    s += wv.x * dd.x + wv.y * dd.y + wv.z * dd.z + wv.w * dd.w;
  }
  s *= dv;
#pragma unroll
  for (int off = 1; off < 64; off <<= 1) s += __shfl_xor(s, off);
  if ((t & 63) == 0) wsum[t >> 6] = s;
  __syncthreads();
  if (t == 0) {
    float k = wsum[0] + wsum[1];
    if (row < N1) inv1[row] = a_ptr[0] * a_ptr[0] / sqrtf(k);
    else inv2[row - N1] = 1.f / sqrtf(k);
  }
}

// ---------------------------------------------------------------------------
// main: one block = 16x16 output tile (256 pairs), 512 threads (8 waves).
//  W in swizzled LDS (round-2-proven); phase-3 A-frags are 8-lane
//  same-address broadcast reads (conflict-free).
//  phase2 (round-4 numerics): per l, 2 MFMA: [hi1|lo1]@[hi2|hi2] +
//    [hi1|lo1]@[lo2|0]; conflict-free permuted table reads; 8 consecutive
//    l batched -> b128 V-writes.
//  phase3: E^T = W @ V^T, folded epilogue (round-4-proven).
// ---------------------------------------------------------------------------
__global__ __launch_bounds__(512, 2) void main_kernel(
    const int* __restrict__ X1, const int* __restrict__ X2,
    const unsigned short* __restrict__ wbg, const unsigned short* __restrict__ Tg,
    const float* __restrict__ inv1, const float* __restrict__ inv2,
    float* __restrict__ out) {
  __shared__ __align__(16) unsigned short sV[256 * LL];  // 64 KB, swizzled
  __shared__ __align__(16) unsigned short sW[LL * LL];   // 32 KB, swizzled
  __shared__ __align__(16) unsigned short sT[3600];      // Thl|Thh|Tl0 (7200 B)
  __shared__ __align__(16) unsigned char x1B[16 * 136];  // bytes [row][l]
  __shared__ __align__(16) unsigned char x2B[16 * 136];

  const int t = threadIdx.x;
  const int lane = t & 63, wave = t >> 6;
  const int m = lane & 15, kg = lane >> 4;
  const int i0 = blockIdx.y * 16, j0 = blockIdx.x * 16;
  char* sVb = reinterpret_cast<char*>(sV);
  char* sWb = reinterpret_cast<char*>(sW);
  char* sTb = reinterpret_cast<char*>(sT);

  // ---- normalization scalars early (global latency hidden under staging) ----
  float iv2 = inv2[j0 + m];
  float iv1a = inv1[i0 + wave * 2];
  float iv1b = inv1[i0 + wave * 2 + 1];

  // ---- stage W: 2048 x 16B chunks, XOR-swizzled ----
#pragma unroll
  for (int c = 0; c < 4; ++c) {
    int ch = c * 512 + t;
    int r = ch >> 4, col8 = ch & 15;
    uint4 v = reinterpret_cast<const uint4*>(wbg)[ch];
    *reinterpret_cast<uint4*>(sWb + r * 256 + ((col8 * 16) ^ ((r & 7) << 4))) = v;
  }
  // ---- stage split tables (7200 B = 450 uint4) ----
  if (t < 450) reinterpret_cast<uint4*>(sT)[t] = reinterpret_cast<const uint4*>(Tg)[t];
  // ---- stage X rows as bytes [row][l], pad 136 ----
  if (t < 256) {
    int row = t >> 4, seg = t & 15;
    const int4* p1 = reinterpret_cast<const int4*>(X1 + (i0 + row) * LL + seg * 8);
    int4 a0 = p1[0], a1 = p1[1];
    unsigned long long v = 0;
    v |= (unsigned long long)(a0.x & 0xff);
    v |= (unsigned long long)(a0.y & 0xff) << 8;
    v |= (unsigned long long)(a0.z & 0xff) << 16;
    v |= (unsigned long long)(a0.w & 0xff) << 24;
    v |= (unsigned long long)(a1.x & 0xff) << 32;
    v |= (unsigned long long)(a1.y & 0xff) << 40;
    v |= (unsigned long long)(a1.z & 0xff) << 48;
    v |= (unsigned long long)(a1.w & 0xff) << 56;
    *reinterpret_cast<unsigned long long*>(x1B + row * 136 + seg * 8) = v;
    const int4* p2 = reinterpret_cast<const int4*>(X2 + (j0 + row) * LL + seg * 8);
    int4 b0 = p2[0], b1 = p2[1];
    unsigned long long u = 0;
    u |= (unsigned long long)(b0.x & 0xff);
    u |= (unsigned long long)(b0.y & 0xff) << 8;
    u |= (unsigned long long)(b0.z & 0xff) << 16;
    u |= (unsigned long long)(b0.w & 0xff) << 24;
    u |= (unsigned long long)(b1.x & 0xff) << 32;
    u |= (unsigned long long)(b1.y & 0xff) << 40;
    u |= (unsigned long long)(b1.z & 0xff) << 48;
    u |= (unsigned long long)(b1.w & 0xff) << 56;
    *reinterpret_cast<unsigned long long*>(x2B + row * 136 + seg * 8) = u;
  }
  __syncthreads();

  // ---- phase 2: V-build. wave owns l in [16w, 16w+16), two 8-l batches ----
  {
#pragma unroll
    for (int half = 0; half < 2; ++half) {
      int l00 = wave * 16 + half * 8;
      unsigned long long w1 = *reinterpret_cast<const unsigned long long*>(x1B + m * 136 + l00);
      unsigned long long w2 = *reinterpret_cast<const unsigned long long*>(x2B + m * 136 + l00);
      f32x4 vq[8];
#pragma unroll
      for (int e = 0; e < 8; ++e) {
        int i1 = (int)((w1 >> (8 * e)) & 0xff);
        int i2 = (int)((w2 >> (8 * e)) & 0xff);
        short8 af = *reinterpret_cast<const short8*>(
            sTb + i1 * 80 + ((kg ^ (i1 >> 3)) << 4));
        short8 bf1 = *reinterpret_cast<const short8*>(
            sTb + 2400 + i2 * 80 + ((kg ^ (i2 >> 3)) << 4));
        short8 bf2 = *reinterpret_cast<const short8*>(
            sTb + 4800 + i2 * 80 + ((kg ^ (i2 >> 3)) << 4));
        f32x4 z = {0.f, 0.f, 0.f, 0.f};
        z = __builtin_amdgcn_mfma_f32_16x16x32_bf16(af, bf1, z, 0, 0, 0);
        z = __builtin_amdgcn_mfma_f32_16x16x32_bf16(af, bf2, z, 0, 0, 0);
        vq[e] = z;
      }
#pragma unroll
      for (int r = 0; r < 4; ++r) {
        uint4 pk;
        pk.x = (unsigned int)f2b(vq[0][r]) | ((unsigned int)f2b(vq[1][r]) << 16);
        pk.y = (unsigned int)f2b(vq[2][r]) | ((unsigned int)f2b(vq[3][r]) << 16);
        pk.z = (unsigned int)f2b(vq[4][r]) | ((unsigned int)f2b(vq[5][r]) << 16);
        pk.w = (unsigned int)f2b(vq[6][r]) | ((unsigned int)f2b(vq[7][r]) << 16);
        int p = (kg * 4 + r) * 16 + m;  // D layout: col=lane&15, row=kg*4+r
        *reinterpret_cast<uint4*>(
            sVb + p * 256 + ((2 * l00) ^ ((p & 7) << 4))) = pk;
      }
    }
  }
  __syncthreads();

  // ---- phase 3: E^T = W @ V^T with folded epilogue ----
  const int pA = (wave * 2) * 16 + m;
  const int pB = (wave * 2 + 1) * 16 + m;
  short8 bvA[4], bvB[4];
#pragma unroll
  for (int kk = 0; kk < 4; ++kk) {
    bvA[kk] = *reinterpret_cast<const short8*>(
        sVb + pA * 256 + ((kk * 64 + kg * 16) ^ ((pA & 7) << 4)));
    bvB[kk] = *reinterpret_cast<const short8*>(
        sVb + pB * 256 + ((kk * 64 + kg * 16) ^ ((pB & 7) << 4)));
  }
  float kp0 = 0.f, kp1 = 0.f;
#pragma unroll
  for (int lt = 0; lt < 8; ++lt) {
    // W A-frags from LDS: 8-lane same-address broadcast, conflict-free
    short8 wA[4];
#pragma unroll
    for (int kk = 0; kk < 4; ++kk)
      wA[kk] = *reinterpret_cast<const short8*>(
          sWb + (lt * 16 + m) * 256 + ((kk * 64 + kg * 16) ^ ((m & 7) << 4)));
    f32x4 a0 = {0.f, 0.f, 0.f, 0.f}, a1 = {0.f, 0.f, 0.f, 0.f};
#pragma unroll
    for (int kk = 0; kk < 4; ++kk) {
      a0 = __builtin_amdgcn_mfma_f32_16x16x32_bf16(wA[kk], bvA[kk], a0, 0, 0, 0);
      a1 = __builtin_amdgcn_mfma_f32_16x16x32_bf16(wA[kk], bvB[kk], a1, 0, 0, 0);
    }
    {
      uint2 vv = *reinterpret_cast<const uint2*>(
          sVb + pA * 256 + ((32 * lt + 8 * kg) ^ ((pA & 7) << 4)));
      float s0 = __uint_as_float(vv.x << 16);
      float s1 = __uint_as_float(vv.x & 0xffff0000u);
      float s2 = __uint_as_float(vv.y << 16);
      float s3 = __uint_as_float(vv.y & 0xffff0000u);
      kp0 += a0[0] * s0 + a0[1] * s1 + a0[2] * s2 + a0[3] * s3;
    }
    {
      uint2 vv = *reinterpret_cast<const uint2*>(
          sVb + pB * 256 + ((32 * lt + 8 * kg) ^ ((pB & 7) << 4)));
      float s0 = __uint_as_float(vv.x << 16);
      float s1 = __uint_as_float(vv.x & 0xffff0000u);
      float s2 = __uint_as_float(vv.y << 16);
      float s3 = __uint_as_float(vv.y & 0xffff0000u);
      kp1 += a1[0] * s0 + a1[1] * s1 + a1[2] * s2 + a1[3] * s3;
    }
  }
  kp0 += __shfl_xor(kp0, 16);
  kp0 += __shfl_xor(kp0, 32);
  kp1 += __shfl_xor(kp1, 16);
  kp1 += __shfl_xor(kp1, 32);
  if (kg == 0) {
    int gi = i0 + wave * 2, gj = j0 + m;
    out[gi * N2 + gj] = kp0 * iv1a * iv2;
    out[(gi + 1) * N2 + gj] = kp1 * iv1b * iv2;
  }
}

// ---------------------------------------------------------------------------
extern "C" void kernel_launch(void* const* d_in, const int* in_sizes, int n_in,
                              void* d_out, int out_size, void* d_ws, size_t ws_size,
                              hipStream_t stream) {
  const int* X1 = (const int*)d_in[0];
  const int* X2 = (const int*)d_in[1];
  const float* a = (const float*)d_in[2];
  const float* A = (const float*)d_in[3];
  const float* w_vec = (const float*)d_in[4];
  float* out = (float*)d_out;

  char* ws = (char*)d_ws;
  float* wf = (float*)(ws + 0);                        // 64 KB
  unsigned short* wb = (unsigned short*)(ws + 65536);  // 32 KB
  float* Sdiag = (float*)(ws + 98304);                 // 128 B
  unsigned short* Tg = (unsigned short*)(ws + 98432);  // 7200 B
  float* inv1 = (float*)(ws + 105728);                 // 3 KB
  float* inv2 = inv1 + N1;                             // 3 KB

  prep_kernel<<<33, 256, 0, stream>>>(A, w_vec, wf, wb, Sdiag, Tg);
  norm_kernel<<<N1 + N2, 128, 0, stream>>>(X1, X2, Sdiag, wf, inv1, inv2, a);
  main_kernel<<<dim3(N2 / 16, N1 / 16), 512, 0, stream>>>(X1, X2, wb, Tg, inv1, inv2, out);
}

// Round 6
// 63.223 us; speedup vs baseline: 2.0185x; 1.1476x over previous
//
#include <hip/hip_runtime.h>
#include <hip/hip_bf16.h>

typedef __attribute__((ext_vector_type(8))) short short8;
typedef __attribute__((ext_vector_type(4))) float f32x4;

#define N1 768
#define N2 768
#define LL 128
#define NS 30

// float -> bf16 bits, round-to-nearest-even (proven rounds 1-5)
__device__ __forceinline__ unsigned short f2b(float f) {
  unsigned int u = __float_as_uint(f);
  unsigned int r = (u + 0x7fffu + ((u >> 16) & 1u)) >> 16;
  return (unsigned short)r;
}

__device__ __forceinline__ float b2f(unsigned short b) {
  return __uint_as_float(((unsigned int)b) << 16);
}

// packed bf16x2 via compiler (RNE, bit-identical to f2b): low=a, high=b
__device__ __forceinline__ unsigned int pack2(float a, float b) {
  __hip_bfloat162 h = __float22bfloat162_rn(make_float2(a, b));
  return *reinterpret_cast<unsigned int*>(&h);
}

// ---------------------------------------------------------------------------
// prep: blocks 1..32: w = sigmoid(W) (f32 + bf16).
//       block 0: Sdiag[s] = ||A[s]||^2; split tables
//         Thl=[hi|lo], Thh=[hi|hi], Tl0=[lo|0], 40 ushorts/row (80 B),
//       16B chunks permuted by chunk ^= (row>>3) (bank-spread, round 5).
// ---------------------------------------------------------------------------
__global__ void prep_kernel(const float* __restrict__ A, const float* __restrict__ w_vec,
                            float* __restrict__ wf, unsigned short* __restrict__ wb,
                            float* __restrict__ Sdiag, unsigned short* __restrict__ Tg) {
  int b = blockIdx.x, t = threadIdx.x;
  if (b == 0) {
    unsigned short* Thl = Tg;
    unsigned short* Thh = Tg + 1200;
    unsigned short* Tl0 = Tg + 2400;
    for (int idx = t; idx < NS * 16; idx += 256) {
      int s = idx >> 4, c = idx & 15, q = s >> 3;
      float v = A[idx];
      unsigned short hi = f2b(v);
      unsigned short lo = f2b(v - b2f(hi));
      int c0 = ((c >> 3) ^ q) * 8 + (c & 7);
      int c2 = (((c >> 3) + 2) ^ q) * 8 + (c & 7);
      Thl[s * 40 + c0] = hi;  Thl[s * 40 + c2] = lo;
      Thh[s * 40 + c0] = hi;  Thh[s * 40 + c2] = hi;
      Tl0[s * 40 + c0] = lo;  Tl0[s * 40 + c2] = 0;
      if (c < 8) {
        Thl[s * 40 + 32 + c] = 0;
        Thh[s * 40 + 32 + c] = 0;
        Tl0[s * 40 + 32 + c] = 0;
      }
    }
    if (t < NS) {
      float acc = 0.f;
#pragma unroll
      for (int c = 0; c < 16; ++c) { float v = A[t * 16 + c]; acc += v * v; }
      Sdiag[t] = acc;
    }
  } else {
    int base = (b - 1) * 512;
#pragma unroll
    for (int k = 0; k < 2; ++k) {
      int idx = base + k * 256 + t;
      int l = idx >> 7, mm = idx & (LL - 1);
      float sig;
      if (l == mm) {
        sig = 0.5f;
      } else {
        int hi = l > mm ? l : mm, lo = l > mm ? mm : l;
        sig = 1.f / (1.f + expf(-w_vec[hi * (hi - 1) / 2 + lo]));
      }
      wf[idx] = sig;
      wb[idx] = f2b(sig);
    }
  }
}

// ---------------------------------------------------------------------------
// norm: one block per row (0..767 -> inv1 with a^2, 768..1535 -> inv2)
// ---------------------------------------------------------------------------
__global__ void norm_kernel(const int* __restrict__ X1, const int* __restrict__ X2,
                            const float* __restrict__ Sdiag, const float* __restrict__ wf,
                            float* __restrict__ inv1, float* __restrict__ inv2,
                            const float* __restrict__ a_ptr) {
  __shared__ __align__(16) float d[LL];
  __shared__ float wsum[2];
  int row = blockIdx.x, t = threadIdx.x;
  const int* X = (row < N1) ? (X1 + row * LL) : (X2 + (row - N1) * LL);
  float dv = Sdiag[X[t]];
  d[t] = dv;
  __syncthreads();
  const float4* w4 = reinterpret_cast<const float4*>(wf + t * LL);
  const float4* d4 = reinterpret_cast<const float4*>(d);
  float s = 0.f;
#pragma unroll
  for (int q = 0; q < LL / 4; ++q) {
    float4 wv = w4[q];
    float4 dd = d4[q];
    s += wv.x * dd.x + wv.y * dd.y + wv.z * dd.z + wv.w * dd.w;
  }
  s *= dv;
#pragma unroll
  for (int off = 1; off < 64; off <<= 1) s += __shfl_xor(s, off);
  if ((t & 63) == 0) wsum[t >> 6] = s;
  __syncthreads();
  if (t == 0) {
    float k = wsum[0] + wsum[1];
    if (row < N1) inv1[row] = a_ptr[0] * a_ptr[0] / sqrtf(k);
    else inv2[row - N1] = 1.f / sqrtf(k);
  }
}

// ---------------------------------------------------------------------------
// main: one block = 16x16 output tile, 512 threads (8 waves), ~77 KB LDS
//   -> 2 blocks/CU co-residency.
//  phase2 (proven numerics): per l, 2 MFMA: [hi1|lo1]@[hi2|hi2] +
//    [hi1|lo1]@[lo2|0]; permuted-table reads; pack2 -> b128 V-writes.
//  phase3: wave w owns l-group lg=w&3 (32 l's, W slice in 32 VGPRs from
//    global) x pair-half ph=w>>2 (8 p-tiles). Per p-tile: 4 b128 V B-frags,
//    8 MFMA, folded epilogue, shfl(16,32) reduce -> red[lg][p] in LDS
//    (aliases index staging); final cross-lg sum + fused scaling store.
// ---------------------------------------------------------------------------
__global__ __launch_bounds__(512, 4) void main_kernel(
    const int* __restrict__ X1, const int* __restrict__ X2,
    const unsigned short* __restrict__ wbg, const unsigned short* __restrict__ Tg,
    const float* __restrict__ inv1, const float* __restrict__ inv2,
    float* __restrict__ out) {
  __shared__ __align__(16) unsigned short sV[256 * LL];  // 64 KB, swizzled
  __shared__ __align__(16) unsigned short sT[3600];      // Thl|Thh|Tl0 (7200 B)
  __shared__ __align__(16) char xred[4352];              // x1B|x2B, later red[4][256]

  const int t = threadIdx.x;
  const int lane = t & 63, wave = t >> 6;
  const int m = lane & 15, kg = lane >> 4;
  const int lg = wave & 3, ph = wave >> 2;
  const int i0 = blockIdx.y * 16, j0 = blockIdx.x * 16;
  char* sVb = reinterpret_cast<char*>(sV);
  char* sTb = reinterpret_cast<char*>(sT);
  unsigned char* x1B = reinterpret_cast<unsigned char*>(xred);         // [16][136]
  unsigned char* x2B = x1B + 2176;
  float* red = reinterpret_cast<float*>(xred);                         // [4][256]

  // ---- W slice for this wave into registers: rows lg*32+lt*16+m ----
  short8 wreg[2][4];
  {
    const char* wby = reinterpret_cast<const char*>(wbg);
#pragma unroll
    for (int lt = 0; lt < 2; ++lt)
#pragma unroll
      for (int kk = 0; kk < 4; ++kk)
        wreg[lt][kk] = *reinterpret_cast<const short8*>(
            wby + (lg * 32 + lt * 16 + m) * 256 + kk * 64 + kg * 16);
  }

  // ---- per-output normalization scalars (used by final store) ----
  float iv1v = 0.f, iv2v = 0.f;
  if (t < 256) {
    iv1v = inv1[i0 + (t >> 4)];
    iv2v = inv2[j0 + (t & 15)];
  }

  // ---- stage split tables (7200 B = 450 uint4) ----
  if (t < 450) reinterpret_cast<uint4*>(sT)[t] = reinterpret_cast<const uint4*>(Tg)[t];
  // ---- stage X rows as bytes [row][l], stride 136 ----
  if (t < 256) {
    int row = t >> 4, seg = t & 15;
    const int4* p1 = reinterpret_cast<const int4*>(X1 + (i0 + row) * LL + seg * 8);
    int4 a0 = p1[0], a1 = p1[1];
    unsigned long long v = 0;
    v |= (unsigned long long)(a0.x & 0xff);
    v |= (unsigned long long)(a0.y & 0xff) << 8;
    v |= (unsigned long long)(a0.z & 0xff) << 16;
    v |= (unsigned long long)(a0.w & 0xff) << 24;
    v |= (unsigned long long)(a1.x & 0xff) << 32;
    v |= (unsigned long long)(a1.y & 0xff) << 40;
    v |= (unsigned long long)(a1.z & 0xff) << 48;
    v |= (unsigned long long)(a1.w & 0xff) << 56;
    *reinterpret_cast<unsigned long long*>(x1B + row * 136 + seg * 8) = v;
    const int4* p2 = reinterpret_cast<const int4*>(X2 + (j0 + row) * LL + seg * 8);
    int4 b0 = p2[0], b1 = p2[1];
    unsigned long long u = 0;
    u |= (unsigned long long)(b0.x & 0xff);
    u |= (unsigned long long)(b0.y & 0xff) << 8;
    u |= (unsigned long long)(b0.z & 0xff) << 16;
    u |= (unsigned long long)(b0.w & 0xff) << 24;
    u |= (unsigned long long)(b1.x & 0xff) << 32;
    u |= (unsigned long long)(b1.y & 0xff) << 40;
    u |= (unsigned long long)(b1.z & 0xff) << 48;
    u |= (unsigned long long)(b1.w & 0xff) << 56;
    *reinterpret_cast<unsigned long long*>(x2B + row * 136 + seg * 8) = u;
  }
  __syncthreads();

  // ---- phase 2: V-build. wave owns l in [16w, 16w+16), two 8-l batches ----
  {
#pragma unroll
    for (int half = 0; half < 2; ++half) {
      int l00 = wave * 16 + half * 8;
      unsigned long long w1 = *reinterpret_cast<const unsigned long long*>(x1B + m * 136 + l00);
      unsigned long long w2 = *reinterpret_cast<const unsigned long long*>(x2B + m * 136 + l00);
      f32x4 vq[8];
#pragma unroll
      for (int e = 0; e < 8; ++e) {
        int i1 = (int)((w1 >> (8 * e)) & 0xff);
        int i2 = (int)((w2 >> (8 * e)) & 0xff);
        short8 af = *reinterpret_cast<const short8*>(
            sTb + i1 * 80 + ((kg ^ (i1 >> 3)) << 4));
        short8 bf1 = *reinterpret_cast<const short8*>(
            sTb + 2400 + i2 * 80 + ((kg ^ (i2 >> 3)) << 4));
        short8 bf2 = *reinterpret_cast<const short8*>(
            sTb + 4800 + i2 * 80 + ((kg ^ (i2 >> 3)) << 4));
        f32x4 z = {0.f, 0.f, 0.f, 0.f};
        z = __builtin_amdgcn_mfma_f32_16x16x32_bf16(af, bf1, z, 0, 0, 0);
        z = __builtin_amdgcn_mfma_f32_16x16x32_bf16(af, bf2, z, 0, 0, 0);
        vq[e] = z;
      }
#pragma unroll
      for (int r = 0; r < 4; ++r) {
        uint4 pk;
        pk.x = pack2(vq[0][r], vq[1][r]);
        pk.y = pack2(vq[2][r], vq[3][r]);
        pk.z = pack2(vq[4][r], vq[5][r]);
        pk.w = pack2(vq[6][r], vq[7][r]);
        int p = (kg * 4 + r) * 16 + m;  // D layout: col=lane&15, row=kg*4+r
        *reinterpret_cast<uint4*>(
            sVb + p * 256 + ((2 * l00) ^ ((p & 7) << 4))) = pk;
      }
    }
  }
  __syncthreads();

  // ---- phase 3: E^T slice = W[lg-rows] @ V^T, folded epilogue ----
#pragma unroll
  for (int pt = 0; pt < 8; ++pt) {
    const int p = ph * 128 + pt * 16 + m;
    short8 bv[4];
#pragma unroll
    for (int kk = 0; kk < 4; ++kk)
      bv[kk] = *reinterpret_cast<const short8*>(
          sVb + p * 256 + ((kk * 64 + kg * 16) ^ ((p & 7) << 4)));
    f32x4 a0 = {0.f, 0.f, 0.f, 0.f}, a1 = {0.f, 0.f, 0.f, 0.f};
#pragma unroll
    for (int kk = 0; kk < 4; ++kk) {
      a0 = __builtin_amdgcn_mfma_f32_16x16x32_bf16(wreg[0][kk], bv[kk], a0, 0, 0, 0);
      a1 = __builtin_amdgcn_mfma_f32_16x16x32_bf16(wreg[1][kk], bv[kk], a1, 0, 0, 0);
    }
    float kp = 0.f;
    {
      uint2 vv = *reinterpret_cast<const uint2*>(
          sVb + p * 256 + ((64 * lg + 8 * kg) ^ ((p & 7) << 4)));
      float s0 = __uint_as_float(vv.x << 16);
      float s1 = __uint_as_float(vv.x & 0xffff0000u);
      float s2 = __uint_as_float(vv.y << 16);
      float s3 = __uint_as_float(vv.y & 0xffff0000u);
      kp += a0[0] * s0 + a0[1] * s1 + a0[2] * s2 + a0[3] * s3;
    }
    {
      uint2 vv = *reinterpret_cast<const uint2*>(
          sVb + p * 256 + ((64 * lg + 32 + 8 * kg) ^ ((p & 7) << 4)));
      float s0 = __uint_as_float(vv.x << 16);
      float s1 = __uint_as_float(vv.x & 0xffff0000u);
      float s2 = __uint_as_float(vv.y << 16);
      float s3 = __uint_as_float(vv.y & 0xffff0000u);
      kp += a1[0] * s0 + a1[1] * s1 + a1[2] * s2 + a1[3] * s3;
    }
    kp += __shfl_xor(kp, 16);
    kp += __shfl_xor(kp, 32);
    if (kg == 0) red[lg * 256 + p] = kp;  // each (lg,p) written by exactly one lane
  }
  __syncthreads();

  // ---- final: cross-lg sum, fused normalization, store ----
  if (t < 256) {
    float s = red[t] + red[256 + t] + red[512 + t] + red[768 + t];
    out[(i0 + (t >> 4)) * N2 + j0 + (t & 15)] = s * iv1v * iv2v;
  }
}

// ---------------------------------------------------------------------------
extern "C" void kernel_launch(void* const* d_in, const int* in_sizes, int n_in,
                              void* d_out, int out_size, void* d_ws, size_t ws_size,
                              hipStream_t stream) {
  const int* X1 = (const int*)d_in[0];
  const int* X2 = (const int*)d_in[1];
  const float* a = (const float*)d_in[2];
  const float* A = (const float*)d_in[3];
  const float* w_vec = (const float*)d_in[4];
  float* out = (float*)d_out;

  char* ws = (char*)d_ws;
  float* wf = (float*)(ws + 0);                        // 64 KB
  unsigned short* wb = (unsigned short*)(ws + 65536);  // 32 KB
  float* Sdiag = (float*)(ws + 98304);                 // 128 B
  unsigned short* Tg = (unsigned short*)(ws + 98432);  // 7200 B
  float* inv1 = (float*)(ws + 105728);                 // 3 KB
  float* inv2 = inv1 + N1;                             // 3 KB

  prep_kernel<<<33, 256, 0, stream>>>(A, w_vec, wf, wb, Sdiag, Tg);
  norm_kernel<<<N1 + N2, 128, 0, stream>>>(X1, X2, Sdiag, wf, inv1, inv2, a);
  main_kernel<<<dim3(N2 / 16, N1 / 16), 512, 0, stream>>>(X1, X2, wb, Tg, inv1, inv2, out);
}